// Round 1
// baseline (99.337 us; speedup 1.0000x reference)
//
#include <hip/hip_runtime.h>

// Bilinear 2x upscale: (16,3,512,512) f32 -> (16,3,1024,1024) f32
// Reference: sy = h * (512/1024) = h*0.5 (exact in fp32), y0=floor, y1=min(y0+1,511),
// weights dy,dx in {0, 0.5} -> all arithmetic exact; matches np reference.

#define N_  16
#define C_  3
#define HI  512
#define WI  512
#define HO  1024
#define WO  1024

__global__ void __launch_bounds__(256)
bilinear2x_kernel(const float* __restrict__ in, float* __restrict__ out) {
    const long long total4 = (long long)N_ * C_ * HO * WO / 4;  // float4 stores
    const long long stride = (long long)gridDim.x * blockDim.x;
    for (long long t = (long long)blockIdx.x * blockDim.x + threadIdx.x;
         t < total4; t += stride) {
        const long long base = t * 4;            // flat output index, multiple of 4
        const int  w0  = (int)(base % WO);       // WO divisible by 4 -> h constant over the 4
        long long  rem = base / WO;
        const int  h   = (int)(rem % HO);
        const long long nc = rem / HO;           // 0..N*C-1

        const float* __restrict__ inp = in + nc * (long long)(HI * WI);

        const float sy = (float)h * 0.5f;        // exact
        const int   y0 = (int)sy;                // h >= 0 -> trunc == floor
        const int   y1 = min(y0 + 1, HI - 1);
        const float dy = sy - (float)y0;         // 0 or 0.5

        const float* __restrict__ r0 = inp + (long long)y0 * WI;
        const float* __restrict__ r1 = inp + (long long)y1 * WI;

        float v[4];
        #pragma unroll
        for (int k = 0; k < 4; ++k) {
            const int   w  = w0 + k;
            const float sx = (float)w * 0.5f;    // exact
            const int   x0 = (int)sx;
            const int   x1 = min(x0 + 1, WI - 1);
            const float dx = sx - (float)x0;     // 0 or 0.5

            const float tl = r0[x0], tr = r0[x1];
            const float bl = r1[x0], br = r1[x1];

            const float top = tl * (1.0f - dx) + tr * dx;   // match ref formula
            const float bot = bl * (1.0f - dx) + br * dx;
            v[k] = top * (1.0f - dy) + bot * dy;
        }

        float4 o;
        o.x = v[0]; o.y = v[1]; o.z = v[2]; o.w = v[3];
        *reinterpret_cast<float4*>(out + base) = o;   // 16B aligned coalesced store
    }
}

extern "C" void kernel_launch(void* const* d_in, const int* in_sizes, int n_in,
                              void* d_out, int out_size, void* d_ws, size_t ws_size,
                              hipStream_t stream) {
    const float* x   = (const float*)d_in[0];
    float*       out = (float*)d_out;

    // Memory-bound: cap grid at 2048 blocks (256 CUs x 8 blocks), grid-stride the rest.
    const dim3 block(256);
    const dim3 grid(2048);
    hipLaunchKernelGGL(bilinear2x_kernel, grid, block, 0, stream, x, out);
}

// Round 2
// 40.574 us; speedup vs baseline: 2.4483x; 2.4483x over previous
//
#include <hip/hip_runtime.h>

// Bilinear 2x upscale: (16,3,512,512) f32 -> (16,3,1024,1024) f32
// All weights are {0, 0.5} (scale exactly 0.5) -> exact fp32, absmax 0 vs np ref.
//
// Layout: one block (256 threads) = one (nc, k) input-row-pair producing output
// rows 2k and 2k+1. Thread j (0..255) produces output cols 4j..4j+3 of both rows
// from input cols 2j..2j+2 of rows k, min(k+1,511).
//   loads : 2x float2 (coalesced) + 2x scalar (L1-hit overlap with lane j+1)
//   stores: 2x float4, lane-contiguous -> 1KB per wave store instruction
// XCD-swizzled blockIdx so consecutive k (which share input row k+1) run on the
// same XCD's L2 -> input fetched ~once from HBM (~50 MB instead of 99 MB).

#define NC_  48          // 16 * 3
#define HI   512
#define WI   512
#define HO   1024
#define WO   1024
#define NBLK (NC_ * HI)  // 24576 blocks, one per (nc, k); divisible by 8

__global__ void __launch_bounds__(256)
bilinear2x_v2(const float* __restrict__ in, float* __restrict__ out) {
    // Bijective XCD swizzle: 24576 % 8 == 0, chunk = 3072 logical blocks/XCD.
    const int l  = (blockIdx.x & 7) * (NBLK / 8) + (blockIdx.x >> 3);
    const int k  = l & (HI - 1);       // input row (output rows 2k, 2k+1)
    const int nc = l >> 9;             // image-channel index, 0..47
    const int j  = threadIdx.x;        // output col-group, 0..255
    const int a  = j << 1;             // input col base, 0..510

    const int y1 = min(k + 1, HI - 1);
    const float* __restrict__ p0 = in + (nc * HI + k)  * WI + a;
    const float* __restrict__ p1 = in + (nc * HI + y1) * WI + a;

    const float2 A0 = *reinterpret_cast<const float2*>(p0);
    const float2 A1 = *reinterpret_cast<const float2*>(p1);
    const int    eo = min(a + 2, WI - 1) - a;   // 2, or 1 at right edge
    const float  E0 = p0[eo];
    const float  E1 = p1[eo];

    // Horizontal interp of source row k (this IS output row 2k: dy = 0)
    const float t0 = A0.x;
    const float t1 = A0.x * 0.5f + A0.y * 0.5f;
    const float t2 = A0.y;
    const float t3 = A0.y * 0.5f + E0 * 0.5f;
    // Horizontal interp of source row k+1
    const float b0 = A1.x;
    const float b1 = A1.x * 0.5f + A1.y * 0.5f;
    const float b2 = A1.y;
    const float b3 = A1.y * 0.5f + E1 * 0.5f;

    float4 o0, o1;
    o0.x = t0; o0.y = t1; o0.z = t2; o0.w = t3;
    // Output row 2k+1: dy = 0.5 -> top*0.5 + bot*0.5 (matches ref op order)
    o1.x = t0 * 0.5f + b0 * 0.5f;
    o1.y = t1 * 0.5f + b1 * 0.5f;
    o1.z = t2 * 0.5f + b2 * 0.5f;
    o1.w = t3 * 0.5f + b3 * 0.5f;

    float* q = out + (nc * HO + (k << 1)) * WO + (j << 2);
    *reinterpret_cast<float4*>(q)      = o0;
    *reinterpret_cast<float4*>(q + WO) = o1;
}

extern "C" void kernel_launch(void* const* d_in, const int* in_sizes, int n_in,
                              void* d_out, int out_size, void* d_ws, size_t ws_size,
                              hipStream_t stream) {
    const float* x   = (const float*)d_in[0];
    float*       out = (float*)d_out;
    hipLaunchKernelGGL(bilinear2x_v2, dim3(NBLK), dim3(256), 0, stream, x, out);
}